// Round 10
// baseline (366.393 us; speedup 1.0000x reference)
//
#include <hip/hip_runtime.h>
#include <hip/hip_bf16.h>
#include <stdint.h>

// GNNStream pipeline.
// gemm_bt (bf16): R6-verified core. MFMA 16x16x32_bf16, 128x128 tile, BK=64 as
//   2x BK=32 XOR-swizzled panels (0 bank conflicts), global_load_lds(16B),
//   LDS-staged coalesced epilogue.
// gemm_qkv: same core; epilogue writes q,k fp8 e4m3 and v fp8 TRANSPOSED.
// gemm_fp8: fp8 GEMM (scores; attn8 x vT8). BK=128. KNOWN: 4.19M LDS bank
//   conflicts (structural 4-way on 8B-aligned b64 frag reads) ~5-7us; todo.
// softmax_adj (R10): 16 rows/block; coords staged to LDS once; per-thread
//   xy+mask hoisted to registers (row-invariant) -- was 80% VALUBusy from
//   per-row scattered gathers (R9: 47us).
// Epilogue loops MUST be fully unrolled: dynamic acc indexing -> scratch spill
//   (R3). mask is int32 on device (harness: integer -> const int*).

typedef __hip_bfloat16 bf16_t;
typedef unsigned char u8;
typedef __attribute__((ext_vector_type(8))) short bf16x8;
typedef __attribute__((ext_vector_type(4))) float f32x4;

__device__ __forceinline__ void cp16_to_lds(const void* g, void* lds) {
  __builtin_amdgcn_global_load_lds(
      (__attribute__((address_space(1))) void*)(g),
      (__attribute__((address_space(3))) void*)(lds), 16, 0, 0);
}

__device__ __forceinline__ uint pk2(float a, float b) {
  bf16_t x = __float2bfloat16(a), y = __float2bfloat16(b);
  return ((uint)(*(ushort*)&y) << 16) | (*(ushort*)&x);
}
__device__ __forceinline__ float bflo(uint u) { return __uint_as_float(u << 16); }
__device__ __forceinline__ float bfhi(uint u) { return __uint_as_float(u & 0xffff0000u); }

// ---------------- bf16 GEMM (R6 core) ----------------
__global__ __launch_bounds__(256) void gemm_bt(
    const bf16_t* __restrict__ A, const bf16_t* __restrict__ B,
    void* __restrict__ Cv, const float* __restrict__ bias, int biasStride,
    float scale, int K, long sA, long sB, long sC, int ldC, int mode)
{
  __shared__ __align__(16) char smem[32768];
  bf16_t* lA = (bf16_t*)smem;
  bf16_t* lB = (bf16_t*)(smem + 16384);
  const int z = blockIdx.z;
  A += (long)z * sA;
  B += (long)z * sB;
  const float* bz = bias ? bias + (long)z * biasStride : nullptr;
  const int m0 = blockIdx.y * 128, n0 = blockIdx.x * 128;
  const int tid = threadIdx.x;
  const int w = tid >> 6, lane = tid & 63;
  const int wm = w >> 1, wn = w & 1;

  const int rr = tid >> 2;
  const int cc = (((tid & 3) ^ ((tid >> 3) & 3)) * 8);
  const bf16_t* a0 = A + (long)(m0 + rr) * K + cc;
  const bf16_t* b0 = B + (long)(n0 + rr) * K + cc;
  const long rowskip = (long)64 * K;

  char* lAc = (char*)lA;
  char* lBc = (char*)lB;
  const int ofs0 = w * 1024;
  const int ofs1 = 4096 + w * 1024;

  f32x4 acc[4][4] = {};
  const int nkt = K >> 6;             // BK=64
  const int quad = lane >> 4;
  const int rsel = lane & 15;
  const int swz = (rsel >> 1) & 3;
  const int kchunkA = (quad ^ swz) * 8;

  for (int kt = 0; kt < nkt; ++kt) {
    __syncthreads();
    cp16_to_lds(a0,                 lAc + ofs0);
    cp16_to_lds(a0 + rowskip,       lAc + ofs1);
    cp16_to_lds(a0 + 32,            lAc + 8192 + ofs0);
    cp16_to_lds(a0 + 32 + rowskip,  lAc + 8192 + ofs1);
    cp16_to_lds(b0,                 lBc + ofs0);
    cp16_to_lds(b0 + rowskip,       lBc + ofs1);
    cp16_to_lds(b0 + 32,            lBc + 8192 + ofs0);
    cp16_to_lds(b0 + 32 + rowskip,  lBc + 8192 + ofs1);
    a0 += 64; b0 += 64;
    __syncthreads();

#pragma unroll
    for (int p = 0; p < 2; ++p) {
      const int pb = p * 4096;
      bf16x8 af[4], bfr[4];
#pragma unroll
      for (int i = 0; i < 4; ++i) {
        af[i]  = *(const bf16x8*)&lA[pb + (wm * 64 + i * 16 + rsel) * 32 + kchunkA];
        bfr[i] = *(const bf16x8*)&lB[pb + (wn * 64 + i * 16 + rsel) * 32 + kchunkA];
      }
#pragma unroll
      for (int i = 0; i < 4; ++i)
#pragma unroll
        for (int j = 0; j < 4; ++j)
          acc[i][j] = __builtin_amdgcn_mfma_f32_16x16x32_bf16(af[i], bfr[j], acc[i][j], 0, 0, 0);
    }
  }

  const int col = lane & 15;
  float bv4[4];
#pragma unroll
  for (int j = 0; j < 4; ++j) {
    const int ng = n0 + wn * 64 + j * 16 + col;
    bv4[j] = bz ? bz[ng] : 0.0f;
  }

  if (mode == 0) {
    char* stb = smem + w * 2176;
    const int nc0 = n0 + wn * 64;
#pragma unroll
    for (int i = 0; i < 4; ++i) {     // FULLY UNROLLED (R3 lesson)
      __syncthreads();
      bf16_t* st = (bf16_t*)stb;
#pragma unroll
      for (int j = 0; j < 4; ++j)
#pragma unroll
        for (int r = 0; r < 4; ++r)
          st[(quad * 4 + r) * 68 + j * 16 + col] =
              __float2bfloat16(acc[i][j][r] * scale + bv4[j]);
      __syncthreads();
      const int row16 = lane >> 2, cseg = lane & 3;
      const long mrow = m0 + wm * 64 + i * 16 + row16;
      bf16_t* cp = (bf16_t*)Cv + (long)z * sC + mrow * ldC + nc0 + cseg * 16;
      const char* sp = stb + row16 * 136 + cseg * 32;
#pragma unroll
      for (int hh = 0; hh < 2; ++hh) {
        uint2 aa = *(const uint2*)(sp + hh * 16);
        uint2 bb = *(const uint2*)(sp + hh * 16 + 8);
        uint4 vv; vv.x = aa.x; vv.y = aa.y; vv.z = bb.x; vv.w = bb.y;
        *(uint4*)(cp + hh * 8) = vv;
      }
    }
  } else {
#pragma unroll
    for (int j = 0; j < 4; ++j) {
      const int ng = n0 + wn * 64 + j * 16 + col;
#pragma unroll
      for (int i = 0; i < 4; ++i) {
        const int mg = m0 + wm * 64 + i * 16 + quad * 4;
#pragma unroll
        for (int r = 0; r < 4; ++r)
          ((float*)Cv)[(long)z * sC + (long)(mg + r) * ldC + ng] =
              acc[i][j][r] * scale + bv4[j];
      }
    }
  }
}

// ---------------- fused q/k/v GEMM ----------------
__global__ __launch_bounds__(256) void gemm_qkv(
    const bf16_t* __restrict__ A, const bf16_t* __restrict__ wT,
    const float* __restrict__ bias_cat, u8* __restrict__ o8,
    u8* __restrict__ vT8)
{
  __shared__ __align__(16) char smem[32768];
  bf16_t* lA = (bf16_t*)smem;
  bf16_t* lB = (bf16_t*)(smem + 16384);
  const int z = blockIdx.z;
  const bf16_t* B = wT + (long)(z + 1) * 262144;
  const float* bz = bias_cat + (long)z * 512;
  const int K = 512;
  const int m0 = blockIdx.y * 128, n0 = blockIdx.x * 128;
  const int tid = threadIdx.x;
  const int w = tid >> 6, lane = tid & 63;
  const int wm = w >> 1, wn = w & 1;

  const int rr = tid >> 2;
  const int cc = (((tid & 3) ^ ((tid >> 3) & 3)) * 8);
  const bf16_t* a0 = A + (long)(m0 + rr) * K + cc;
  const bf16_t* b0 = B + (long)(n0 + rr) * K + cc;
  const long rowskip = (long)64 * K;

  char* lAc = (char*)lA;
  char* lBc = (char*)lB;
  const int ofs0 = w * 1024;
  const int ofs1 = 4096 + w * 1024;

  f32x4 acc[4][4] = {};
  const int quad = lane >> 4;
  const int rsel = lane & 15;
  const int swz = (rsel >> 1) & 3;
  const int kchunkA = (quad ^ swz) * 8;

  for (int kt = 0; kt < 8; ++kt) {
    __syncthreads();
    cp16_to_lds(a0,                 lAc + ofs0);
    cp16_to_lds(a0 + rowskip,       lAc + ofs1);
    cp16_to_lds(a0 + 32,            lAc + 8192 + ofs0);
    cp16_to_lds(a0 + 32 + rowskip,  lAc + 8192 + ofs1);
    cp16_to_lds(b0,                 lBc + ofs0);
    cp16_to_lds(b0 + rowskip,       lBc + ofs1);
    cp16_to_lds(b0 + 32,            lBc + 8192 + ofs0);
    cp16_to_lds(b0 + 32 + rowskip,  lBc + 8192 + ofs1);
    a0 += 64; b0 += 64;
    __syncthreads();

#pragma unroll
    for (int p = 0; p < 2; ++p) {
      const int pb = p * 4096;
      bf16x8 af[4], bfr[4];
#pragma unroll
      for (int i = 0; i < 4; ++i) {
        af[i]  = *(const bf16x8*)&lA[pb + (wm * 64 + i * 16 + rsel) * 32 + kchunkA];
        bfr[i] = *(const bf16x8*)&lB[pb + (wn * 64 + i * 16 + rsel) * 32 + kchunkA];
      }
#pragma unroll
      for (int i = 0; i < 4; ++i)
#pragma unroll
        for (int j = 0; j < 4; ++j)
          acc[i][j] = __builtin_amdgcn_mfma_f32_16x16x32_bf16(af[i], bfr[j], acc[i][j], 0, 0, 0);
    }
  }

  const int col = lane & 15;
  float bv4[4];
#pragma unroll
  for (int j = 0; j < 4; ++j) bv4[j] = bz[n0 + wn * 64 + j * 16 + col];
  const int nc0 = n0 + wn * 64;

  if (z < 2) {
    u8* stb = (u8*)(smem + w * 2176);
    u8* O = o8 + (long)z * 8388608;
#pragma unroll
    for (int i = 0; i < 4; ++i) {
      __syncthreads();
#pragma unroll
      for (int j = 0; j < 4; ++j) {
        uint pk = 0;
        pk = __builtin_amdgcn_cvt_pk_fp8_f32(acc[i][j][0] + bv4[j],
                                             acc[i][j][1] + bv4[j], pk, false);
        pk = __builtin_amdgcn_cvt_pk_fp8_f32(acc[i][j][2] + bv4[j],
                                             acc[i][j][3] + bv4[j], pk, true);
        stb[(quad * 4 + 0) * 72 + j * 16 + col] = (u8)(pk);
        stb[(quad * 4 + 1) * 72 + j * 16 + col] = (u8)(pk >> 8);
        stb[(quad * 4 + 2) * 72 + j * 16 + col] = (u8)(pk >> 16);
        stb[(quad * 4 + 3) * 72 + j * 16 + col] = (u8)(pk >> 24);
      }
      __syncthreads();
      const int trow = lane >> 2, seg = lane & 3;
      const long mrow = m0 + wm * 64 + i * 16 + trow;
      *(uint4*)(O + mrow * 512 + nc0 + seg * 16) =
          *(const uint4*)(stb + trow * 72 + seg * 16);
    }
  } else {
    u8* st8 = (u8*)(smem + w * 2176);
    const int bt = blockIdx.y >> 4;
    const int t0g = (m0 & 2047) + wm * 64;
#pragma unroll
    for (int j = 0; j < 4; ++j) {
      __syncthreads();
#pragma unroll
      for (int i = 0; i < 4; ++i) {
        uint pk = 0;
        pk = __builtin_amdgcn_cvt_pk_fp8_f32(acc[i][j][0] + bv4[j],
                                             acc[i][j][1] + bv4[j], pk, false);
        pk = __builtin_amdgcn_cvt_pk_fp8_f32(acc[i][j][2] + bv4[j],
                                             acc[i][j][3] + bv4[j], pk, true);
        *(uint*)&st8[col * 72 + i * 16 + quad * 4] = pk;
      }
      __syncthreads();
      const int drow = lane >> 2, seg = lane & 3;
      const int d = nc0 + j * 16 + drow;
      u8* dst = vT8 + ((long)(bt * 512 + d)) * 2048 + t0g;
      *(uint4*)(dst + seg * 16) = *(const uint4*)(st8 + drow * 72 + seg * 16);
    }
  }
}

// ---------------- generalized fp8 GEMM ----------------
__global__ __launch_bounds__(256) void gemm_fp8(
    const u8* __restrict__ A, const u8* __restrict__ B,
    bf16_t* __restrict__ C, float scale, int K,
    long sA, long sB, long sC, int ldC)
{
  __shared__ __align__(16) char smem[32768];
  const int z = blockIdx.z;
  A += (long)z * sA;
  B += (long)z * sB;
  const int m0 = blockIdx.y * 128, n0 = blockIdx.x * 128;
  const int tid = threadIdx.x;
  const int w = tid >> 6, lane = tid & 63;
  const int wm = w >> 1, wn = w & 1;

  const int rr = tid >> 2;
  const int ccB = (((tid & 3) ^ ((tid >> 3) & 3)) * 16);
  const u8* a0 = A + (long)(m0 + rr) * K + ccB;
  const u8* b0 = B + (long)(n0 + rr) * K + ccB;
  const long rowskip = (long)64 * K;

  char* lAc = smem;
  char* lBc = smem + 16384;
  const int ofs0 = w * 1024;
  const int ofs1 = 4096 + w * 1024;

  f32x4 acc[4][4] = {};
  const int quad = lane >> 4;
  const int rsel = lane & 15;
  const int swz = (rsel >> 1) & 3;

  const int nkt = K >> 7;             // BK=128
  for (int kt = 0; kt < nkt; ++kt) {
    __syncthreads();
    cp16_to_lds(a0,                  lAc + ofs0);
    cp16_to_lds(a0 + rowskip,        lAc + ofs1);
    cp16_to_lds(a0 + 64,             lAc + 8192 + ofs0);
    cp16_to_lds(a0 + 64 + rowskip,   lAc + 8192 + ofs1);
    cp16_to_lds(b0,                  lBc + ofs0);
    cp16_to_lds(b0 + rowskip,        lBc + ofs1);
    cp16_to_lds(b0 + 64,             lBc + 8192 + ofs0);
    cp16_to_lds(b0 + 64 + rowskip,   lBc + 8192 + ofs1);
    a0 += 128; b0 += 128;
    __syncthreads();

#pragma unroll
    for (int p = 0; p < 2; ++p) {
      const int pb = p * 8192;
#pragma unroll
      for (int ks = 0; ks < 2; ++ks) {
        const int gr = ((ks * 2 + (quad >> 1)) ^ swz) * 16 + (quad & 1) * 8;
        long av[4], bv[4];
#pragma unroll
        for (int i = 0; i < 4; ++i) {
          av[i] = *(const long*)(lAc + pb + (wm * 64 + i * 16 + rsel) * 64 + gr);
          bv[i] = *(const long*)(lBc + pb + (wn * 64 + i * 16 + rsel) * 64 + gr);
        }
#pragma unroll
        for (int i = 0; i < 4; ++i)
#pragma unroll
          for (int j = 0; j < 4; ++j)
            acc[i][j] = __builtin_amdgcn_mfma_f32_16x16x32_fp8_fp8(av[i], bv[j], acc[i][j], 0, 0, 0);
      }
    }
  }

  const int col = lane & 15;
  char* stb = smem + w * 2176;
  const int nc0 = n0 + wn * 64;
#pragma unroll
  for (int i = 0; i < 4; ++i) {
    __syncthreads();
    bf16_t* st = (bf16_t*)stb;
#pragma unroll
    for (int j = 0; j < 4; ++j)
#pragma unroll
      for (int r = 0; r < 4; ++r)
        st[(quad * 4 + r) * 68 + j * 16 + col] =
            __float2bfloat16(acc[i][j][r] * scale);
    __syncthreads();
    const int row16 = lane >> 2, cseg = lane & 3;
    const long mrow = m0 + wm * 64 + i * 16 + row16;
    bf16_t* cp = C + (long)z * sC + mrow * ldC + nc0 + cseg * 16;
    const char* sp = stb + row16 * 136 + cseg * 32;
#pragma unroll
    for (int hh = 0; hh < 2; ++hh) {
      uint2 aa = *(const uint2*)(sp + hh * 16);
      uint2 bb = *(const uint2*)(sp + hh * 16 + 8);
      uint4 vv; vv.x = aa.x; vv.y = aa.y; vv.z = bb.x; vv.w = bb.y;
      *(uint4*)(cp + hh * 8) = vv;
    }
  }
}

// ---------------- small kernels ----------------
__global__ __launch_bounds__(256) void weight_prep(
    const float* __restrict__ w0, const float* __restrict__ w1,
    const float* __restrict__ w2, const float* __restrict__ w3,
    const float* __restrict__ w4,
    const float* __restrict__ bq, const float* __restrict__ bk,
    const float* __restrict__ bv,
    bf16_t* __restrict__ outT, float* __restrict__ bias_cat)
{
  const int z = blockIdx.z;
  const int N = (z == 4) ? 256 : 512;
  if (z == 4 && blockIdx.y >= 4) return;
  const float* in = (z == 0) ? w0 : (z == 1) ? w1 : (z == 2) ? w2 : (z == 3) ? w3 : w4;
  bf16_t* out = outT + (long)z * 262144;
  const int k0 = blockIdx.x * 64, n0 = blockIdx.y * 64;
  __shared__ bf16_t tile[64 * 66];
  const int tid = threadIdx.x;
  const int r = tid >> 2, c4 = tid & 3;
  const float* src = in + (long)(k0 + r) * N + n0 + c4 * 16;
  uint* dst = (uint*)&tile[r * 66 + c4 * 16];
  float4 f0 = ((const float4*)src)[0], f1 = ((const float4*)src)[1];
  float4 f2 = ((const float4*)src)[2], f3 = ((const float4*)src)[3];
  dst[0] = pk2(f0.x, f0.y); dst[1] = pk2(f0.z, f0.w);
  dst[2] = pk2(f1.x, f1.y); dst[3] = pk2(f1.z, f1.w);
  dst[4] = pk2(f2.x, f2.y); dst[5] = pk2(f2.z, f2.w);
  dst[6] = pk2(f3.x, f3.y); dst[7] = pk2(f3.z, f3.w);
  __syncthreads();
  bf16_t* og = out + (long)(n0 + r) * 512 + k0 + c4 * 16;
  uint ov[8];
#pragma unroll
  for (int j = 0; j < 16; j += 2) {
    const ushort lo = *(const ushort*)&tile[(c4 * 16 + j) * 66 + r];
    const ushort hi = *(const ushort*)&tile[(c4 * 16 + j + 1) * 66 + r];
    ov[j >> 1] = ((uint)hi << 16) | lo;
  }
  uint4 o0, o1;
  o0.x = ov[0]; o0.y = ov[1]; o0.z = ov[2]; o0.w = ov[3];
  o1.x = ov[4]; o1.y = ov[5]; o1.z = ov[6]; o1.w = ov[7];
  ((uint4*)og)[0] = o0;
  ((uint4*)og)[1] = o1;
  if (z >= 1 && z <= 3 && blockIdx.x == 0 && blockIdx.y == 0) {
    const float* bs = (z == 1) ? bq : (z == 2) ? bk : bv;
    bias_cat[(z - 1) * 512 + tid] = bs[tid];
    bias_cat[(z - 1) * 512 + 256 + tid] = bs[256 + tid];
  }
}

__global__ __launch_bounds__(256) void cast_bf16_v(
    const float4* __restrict__ in, uint2* __restrict__ o, int n4) {
  const int i = blockIdx.x * 256 + threadIdx.x;
  if (i < n4) {
    const float4 f = in[i];
    uint2 r; r.x = pk2(f.x, f.y); r.y = pk2(f.z, f.w);
    o[i] = r;
  }
}

// in-place LayerNorm(512)+ReLU, one wave per row, 8 bf16/lane, shuffle-only.
__global__ __launch_bounds__(256) void ln_relu_h(
    bf16_t* __restrict__ X, const float* __restrict__ g, const float* __restrict__ b)
{
  const int tid = threadIdx.x;
  const int lane = tid & 63, w = tid >> 6;
  const long row = (long)blockIdx.x * 4 + w;
  bf16_t* xp = X + row * 512 + lane * 8;
  const uint4 pkv = *(const uint4*)xp;
  const uint va[4] = {pkv.x, pkv.y, pkv.z, pkv.w};
  float v[8];
  float s = 0.0f, q = 0.0f;
#pragma unroll
  for (int i = 0; i < 4; ++i) {
    v[2 * i] = bflo(va[i]); v[2 * i + 1] = bfhi(va[i]);
    s += v[2 * i] + v[2 * i + 1];
    q += v[2 * i] * v[2 * i] + v[2 * i + 1] * v[2 * i + 1];
  }
  for (int o = 32; o; o >>= 1) { s += __shfl_down(s, o); q += __shfl_down(q, o); }
  s = __shfl(s, 0); q = __shfl(q, 0);
  const float mu = s * (1.0f / 512.0f);
  const float rs = rsqrtf(q * (1.0f / 512.0f) - mu * mu + 1e-5f);
  const float4 g0 = ((const float4*)(g + lane * 8))[0], g1 = ((const float4*)(g + lane * 8))[1];
  const float4 b0 = ((const float4*)(b + lane * 8))[0], b1 = ((const float4*)(b + lane * 8))[1];
  const float gg[8] = {g0.x, g0.y, g0.z, g0.w, g1.x, g1.y, g1.z, g1.w};
  const float bb[8] = {b0.x, b0.y, b0.z, b0.w, b1.x, b1.y, b1.z, b1.w};
  uint ov[4];
#pragma unroll
  for (int i = 0; i < 4; ++i) {
    const float y0 = fmaxf((v[2 * i] - mu) * rs * gg[2 * i] + bb[2 * i], 0.0f);
    const float y1 = fmaxf((v[2 * i + 1] - mu) * rs * gg[2 * i + 1] + bb[2 * i + 1], 0.0f);
    ov[i] = pk2(y0, y1);
  }
  uint4 st; st.x = ov[0]; st.y = ov[1]; st.z = ov[2]; st.w = ov[3];
  *(uint4*)xp = st;
}

// softmax over 2048 + *exp(-5 dist) * (!mask) -> fp8(val*256).
// 16 rows per block; coords staged to LDS once; per-thread xy/mask hoisted.
__global__ __launch_bounds__(256) void softmax_adj(
    const bf16_t* __restrict__ SC, u8* __restrict__ A8,
    const float* __restrict__ coords, const int* __restrict__ mask)
{
  __shared__ float ldsC[6144];          // batch coords, raw xyz interleaved
  __shared__ float sm[8];
  const int b = blockIdx.x >> 7;        // 128 blocks per batch
  const int s0 = (blockIdx.x & 127) * 16;
  const int tid = threadIdx.x;
  const int w = tid >> 6, lane = tid & 63;

  const float4* csrc = (const float4*)(coords + (long)b * 6144);
#pragma unroll
  for (int k = 0; k < 6; ++k)
    *(float4*)&ldsC[(tid + k * 256) * 4] = csrc[tid + k * 256];

  const int t0 = tid * 8;
  int msk[8];
  {
    const int4 m0 = *(const int4*)(mask + b * 2048 + t0);
    const int4 m1 = *(const int4*)(mask + b * 2048 + t0 + 4);
    msk[0] = m0.x; msk[1] = m0.y; msk[2] = m0.z; msk[3] = m0.w;
    msk[4] = m1.x; msk[5] = m1.y; msk[6] = m1.z; msk[7] = m1.w;
  }
  __syncthreads();
  float cx[8], cy[8];
#pragma unroll
  for (int i = 0; i < 8; ++i) {
    cx[i] = ldsC[(t0 + i) * 3];
    cy[i] = ldsC[(t0 + i) * 3 + 1];
  }

  for (int r = 0; r < 16; ++r) {
    const int s = s0 + r;
    const long base = ((long)b * 2048 + s) * 2048;
    const uint4 pkv = *(const uint4*)(SC + base + t0);
    const uint va[4] = {pkv.x, pkv.y, pkv.z, pkv.w};
    float rv[8];
    float mx = -3.0e38f;
#pragma unroll
    for (int i = 0; i < 4; ++i) {
      rv[2 * i] = bflo(va[i]); rv[2 * i + 1] = bfhi(va[i]);
      mx = fmaxf(mx, fmaxf(rv[2 * i], rv[2 * i + 1]));
    }
    for (int o = 32; o; o >>= 1) mx = fmaxf(mx, __shfl_down(mx, o));
    if (!lane) sm[w] = mx;
    __syncthreads();
    mx = fmaxf(fmaxf(sm[0], sm[1]), fmaxf(sm[2], sm[3]));
    float sum = 0.0f;
#pragma unroll
    for (int i = 0; i < 8; ++i) { rv[i] = __expf(rv[i] - mx); sum += rv[i]; }
    for (int o = 32; o; o >>= 1) sum += __shfl_down(sum, o);
    if (!lane) sm[4 + w] = sum;
    __syncthreads();
    const float inv = 256.0f / (sm[4] + sm[5] + sm[6] + sm[7]);
    const float px = ldsC[3 * s], py = ldsC[3 * s + 1];
    float ov[8];
#pragma unroll
    for (int i = 0; i < 8; ++i) {
      const float dx = px - cx[i], dy = py - cy[i];
      const float adj = __expf(-5.0f * sqrtf(dx * dx + dy * dy));
      ov[i] = msk[i] ? 0.0f : rv[i] * inv * adj;
    }
    uint p0 = 0, p1 = 0;
    p0 = __builtin_amdgcn_cvt_pk_fp8_f32(ov[0], ov[1], p0, false);
    p0 = __builtin_amdgcn_cvt_pk_fp8_f32(ov[2], ov[3], p0, true);
    p1 = __builtin_amdgcn_cvt_pk_fp8_f32(ov[4], ov[5], p1, false);
    p1 = __builtin_amdgcn_cvt_pk_fp8_f32(ov[6], ov[7], p1, true);
    uint2 st; st.x = p0; st.y = p1;
    *(uint2*)(A8 + base + t0) = st;
  }
}

// LayerNorm(256)+ReLU on f32 rows, masked accumulate into pooled_acc[b][256]
__global__ __launch_bounds__(256) void ln2_pool(
    const float* __restrict__ X, const float* __restrict__ g, const float* __restrict__ bt,
    const int* __restrict__ mask, float* __restrict__ pacc)
{
  const int tid = threadIdx.x;
  const int row0 = blockIdx.x * 16;
  const int w = tid >> 6, lane = tid & 63;
  __shared__ float sm[8];
  const float gv = g[tid], bv = bt[tid];
  float acc = 0.0f;
  for (int r = 0; r < 16; ++r) {
    const int row = row0 + r;
    const float x = X[(long)row * 256 + tid];
    float s = x, q = x * x;
    for (int o = 32; o; o >>= 1) { s += __shfl_down(s, o); q += __shfl_down(q, o); }
    if (!lane) { sm[w] = s; sm[4 + w] = q; }
    __syncthreads();
    const float S = sm[0] + sm[1] + sm[2] + sm[3];
    const float Q = sm[4] + sm[5] + sm[6] + sm[7];
    const float mu = S * (1.0f / 256.0f);
    const float rs = rsqrtf(Q * (1.0f / 256.0f) - mu * mu + 1e-5f);
    const float y = fmaxf((x - mu) * rs * gv + bv, 0.0f);
    if (!mask[row]) acc += y;
    __syncthreads();
  }
  atomicAdd(&pacc[(row0 >> 11) * 256 + tid], acc);
}

__global__ __launch_bounds__(256) void classifier_k(
    const float* __restrict__ pacc, const int* __restrict__ mask,
    const float* __restrict__ w1, const float* __restrict__ b1,
    const float* __restrict__ w2, const float* __restrict__ b2,
    float* __restrict__ out)
{
  const int tid = threadIdx.x;
  __shared__ float pooled[2048];
  __shared__ float hidden[1024];
  __shared__ float cnt[8];
  if (tid < 8) cnt[tid] = 0.0f;
  __syncthreads();
  {
    const int* mb = mask + tid * 64;
    int c = 0;
#pragma unroll 8
    for (int i = 0; i < 64; ++i) c += mb[i] ? 0 : 1;
    atomicAdd(&cnt[tid >> 5], (float)c);
  }
  __syncthreads();
  for (int i = tid; i < 2048; i += 256) {
    const float p = pacc[i] / fmaxf(cnt[i >> 8], 1e-9f);
    pooled[i] = p;
    out[80 + i] = p;
  }
  __syncthreads();
  for (int o = tid; o < 1024; o += 256) {
    const int bb = o >> 7, j = o & 127;
    float s = b1[j];
    const float* pb = pooled + bb * 256;
    for (int c = 0; c < 256; ++c) s += pb[c] * w1[c * 128 + j];
    hidden[o] = fmaxf(s, 0.0f);
  }
  __syncthreads();
  if (tid < 80) {
    const int bb = tid / 10, j = tid - bb * 10;
    float s = b2[j];
    const float* hb = hidden + bb * 128;
    for (int c = 0; c < 128; ++c) s += hb[c] * w2[c * 10 + j];
    out[tid] = s;
  }
}

extern "C" void kernel_launch(void* const* d_in, const int* in_sizes, int n_in,
                              void* d_out, int out_size, void* d_ws, size_t ws_size,
                              hipStream_t stream)
{
  const float* lf   = (const float*)d_in[0];
  const float* co   = (const float*)d_in[1];
  const int*   mk   = (const int*)d_in[2];
  const float* wenc = (const float*)d_in[3];
  const float* benc = (const float*)d_in[4];
  const float* g1   = (const float*)d_in[5];
  const float* be1  = (const float*)d_in[6];
  const float* wq   = (const float*)d_in[7];
  const float* bq   = (const float*)d_in[8];
  const float* wk   = (const float*)d_in[9];
  const float* bk   = (const float*)d_in[10];
  const float* wv   = (const float*)d_in[11];
  const float* bvp  = (const float*)d_in[12];
  const float* wbn  = (const float*)d_in[13];
  const float* bbn  = (const float*)d_in[14];
  const float* g2   = (const float*)d_in[15];
  const float* be2  = (const float*)d_in[16];
  const float* w1   = (const float*)d_in[17];
  const float* b1   = (const float*)d_in[18];
  const float* w2   = (const float*)d_in[19];
  const float* b2   = (const float*)d_in[20];
  float* out = (float*)d_out;
  char* ws = (char*)d_ws;

  bf16_t* featb = (bf16_t*)(ws + 0);              // 16 MB
  bf16_t* wT    = (bf16_t*)(ws + 16777216);       // 5 x 512KB slots
  bf16_t* wencT = wT;
  bf16_t* wbnT  = wT + 4 * 262144;
  float*  bias_cat = (float*)(ws + 19398656);     // 8 KB
  bf16_t* h     = (bf16_t*)(ws + 19406848);       // 16 MB -> ends 36184064
  u8*     q8    = (u8*)(ws + 36184064);           // 16 MB (q8, k8) -> 52961280
  u8*     vT8   = (u8*)(ws + 52961280);           // 8 MB -> 61349888
  bf16_t* sc    = (bf16_t*)(ws + 61349888);       // 64 MB -> 128458752
  u8*     at8   = (u8*)(ws + 128458752);          // 32 MB -> 162013184
  bf16_t* hg    = (bf16_t*)(ws + 0);              // reuse featb
  float*  bnp   = (float*)(ws + 36184064);        // reuse q8/k8 (16 MB f32)
  float*  pacc  = (float*)(ws + 52961280);        // reuse vT8 head (8 KB)

  if (ws_size < 162013184) return;  // fail visibly rather than fault

  cast_bf16_v<<<8192, 256, 0, stream>>>((const float4*)lf, (uint2*)featb, 2097152);
  weight_prep<<<dim3(8, 8, 5), 256, 0, stream>>>(wenc, wq, wk, wv, wbn, bq, bk, bvp,
                                                 wT, bias_cat);

  // h_pre = feat @ w_enc + b_enc
  gemm_bt<<<dim3(4, 128, 1), 256, 0, stream>>>(featb, wencT, h, benc, 0, 1.0f, 512,
                                               0, 0, 0, 512, 0);
  ln_relu_h<<<4096, 256, 0, stream>>>(h, g1, be1);
  // q,k (fp8 natural) + v (fp8 transposed) in one launch
  gemm_qkv<<<dim3(4, 128, 3), 256, 0, stream>>>(h, wT, bias_cat, q8, vT8);
  // scores[b] = q_b k_b^T / sqrt(512)  (fp8 in, bf16 out)
  gemm_fp8<<<dim3(16, 16, 8), 256, 0, stream>>>(q8, q8 + 8388608, sc,
                                                0.044194173824159216f, 512,
                                                1048576, 1048576, 4194304, 2048);
  // softmax + adj + mask -> attn8 (fp8 x256); 16 rows/block
  softmax_adj<<<1024, 256, 0, stream>>>(sc, at8, co, mk);
  // hg[b] = attn_b @ v_b  (fp8 in, bf16 out, scale 1/256)
  gemm_fp8<<<dim3(4, 16, 8), 256, 0, stream>>>(at8, vT8, hg, 0.00390625f, 2048,
                                               4194304, 1048576, 1048576, 512);
  // bn_pre = hg @ w_bn + b_bn  (f32 out)
  gemm_bt<<<dim3(2, 128, 1), 256, 0, stream>>>(hg, wbnT, bnp, bbn, 0, 1.0f, 512,
                                               0, 0, 0, 256, 2);
  hipMemsetAsync(pacc, 0, 8192, stream);
  ln2_pool<<<1024, 256, 0, stream>>>(bnp, g2, be2, mk, pacc);
  classifier_k<<<1, 256, 0, stream>>>(pacc, mk, w1, b1, w2, b2, out);
}

// Round 12
// 359.239 us; speedup vs baseline: 1.0199x; 1.0199x over previous
//
#include <hip/hip_runtime.h>
#include <hip/hip_bf16.h>
#include <stdint.h>

// GNNStream pipeline.
// gemm_bt (bf16): R6-verified core. MFMA 16x16x32_bf16, 128x128 tile, BK=64 as
//   2x BK=32 XOR-swizzled panels (0 bank conflicts), global_load_lds(16B),
//   LDS-staged coalesced epilogue.
// gemm_qkv: same core; epilogue writes q,k fp8 e4m3 and v fp8 TRANSPOSED.
// gemm_fp8: fp8 GEMM (scores; attn8 x vT8). BK=128. KNOWN: ~4/read LDS
//   "conflict" cycles on b64 frag reads (structural); fp8 still beats bf16.
// softmax_adj (R11): one row/block (R9 70%-occupancy shape; R10's 25KB-LDS
//   16-row version tanked occupancy 70->30 and regressed). Target xy/mask
//   pre-packed by pack_xy into float2/u8 arrays -> 4 coalesced float4 loads
//   replace 16 stride-12B scalar gathers (R9's 80% VALUBusy cause).
// Epilogue loops MUST be fully unrolled: dynamic acc indexing -> scratch spill
//   (R3). mask is int32 on device (harness: integer -> const int*).
// R11 bench was an infra failure (container provisioning); this is an
// unchanged resubmit.

typedef __hip_bfloat16 bf16_t;
typedef unsigned char u8;
typedef __attribute__((ext_vector_type(8))) short bf16x8;
typedef __attribute__((ext_vector_type(4))) float f32x4;

__device__ __forceinline__ void cp16_to_lds(const void* g, void* lds) {
  __builtin_amdgcn_global_load_lds(
      (__attribute__((address_space(1))) void*)(g),
      (__attribute__((address_space(3))) void*)(lds), 16, 0, 0);
}

__device__ __forceinline__ uint pk2(float a, float b) {
  bf16_t x = __float2bfloat16(a), y = __float2bfloat16(b);
  return ((uint)(*(ushort*)&y) << 16) | (*(ushort*)&x);
}
__device__ __forceinline__ float bflo(uint u) { return __uint_as_float(u << 16); }
__device__ __forceinline__ float bfhi(uint u) { return __uint_as_float(u & 0xffff0000u); }

// ---------------- bf16 GEMM (R6 core) ----------------
__global__ __launch_bounds__(256) void gemm_bt(
    const bf16_t* __restrict__ A, const bf16_t* __restrict__ B,
    void* __restrict__ Cv, const float* __restrict__ bias, int biasStride,
    float scale, int K, long sA, long sB, long sC, int ldC, int mode)
{
  __shared__ __align__(16) char smem[32768];
  bf16_t* lA = (bf16_t*)smem;
  bf16_t* lB = (bf16_t*)(smem + 16384);
  const int z = blockIdx.z;
  A += (long)z * sA;
  B += (long)z * sB;
  const float* bz = bias ? bias + (long)z * biasStride : nullptr;
  const int m0 = blockIdx.y * 128, n0 = blockIdx.x * 128;
  const int tid = threadIdx.x;
  const int w = tid >> 6, lane = tid & 63;
  const int wm = w >> 1, wn = w & 1;

  const int rr = tid >> 2;
  const int cc = (((tid & 3) ^ ((tid >> 3) & 3)) * 8);
  const bf16_t* a0 = A + (long)(m0 + rr) * K + cc;
  const bf16_t* b0 = B + (long)(n0 + rr) * K + cc;
  const long rowskip = (long)64 * K;

  char* lAc = (char*)lA;
  char* lBc = (char*)lB;
  const int ofs0 = w * 1024;
  const int ofs1 = 4096 + w * 1024;

  f32x4 acc[4][4] = {};
  const int nkt = K >> 6;             // BK=64
  const int quad = lane >> 4;
  const int rsel = lane & 15;
  const int swz = (rsel >> 1) & 3;
  const int kchunkA = (quad ^ swz) * 8;

  for (int kt = 0; kt < nkt; ++kt) {
    __syncthreads();
    cp16_to_lds(a0,                 lAc + ofs0);
    cp16_to_lds(a0 + rowskip,       lAc + ofs1);
    cp16_to_lds(a0 + 32,            lAc + 8192 + ofs0);
    cp16_to_lds(a0 + 32 + rowskip,  lAc + 8192 + ofs1);
    cp16_to_lds(b0,                 lBc + ofs0);
    cp16_to_lds(b0 + rowskip,       lBc + ofs1);
    cp16_to_lds(b0 + 32,            lBc + 8192 + ofs0);
    cp16_to_lds(b0 + 32 + rowskip,  lBc + 8192 + ofs1);
    a0 += 64; b0 += 64;
    __syncthreads();

#pragma unroll
    for (int p = 0; p < 2; ++p) {
      const int pb = p * 4096;
      bf16x8 af[4], bfr[4];
#pragma unroll
      for (int i = 0; i < 4; ++i) {
        af[i]  = *(const bf16x8*)&lA[pb + (wm * 64 + i * 16 + rsel) * 32 + kchunkA];
        bfr[i] = *(const bf16x8*)&lB[pb + (wn * 64 + i * 16 + rsel) * 32 + kchunkA];
      }
#pragma unroll
      for (int i = 0; i < 4; ++i)
#pragma unroll
        for (int j = 0; j < 4; ++j)
          acc[i][j] = __builtin_amdgcn_mfma_f32_16x16x32_bf16(af[i], bfr[j], acc[i][j], 0, 0, 0);
    }
  }

  const int col = lane & 15;
  float bv4[4];
#pragma unroll
  for (int j = 0; j < 4; ++j) {
    const int ng = n0 + wn * 64 + j * 16 + col;
    bv4[j] = bz ? bz[ng] : 0.0f;
  }

  if (mode == 0) {
    char* stb = smem + w * 2176;
    const int nc0 = n0 + wn * 64;
#pragma unroll
    for (int i = 0; i < 4; ++i) {     // FULLY UNROLLED (R3 lesson)
      __syncthreads();
      bf16_t* st = (bf16_t*)stb;
#pragma unroll
      for (int j = 0; j < 4; ++j)
#pragma unroll
        for (int r = 0; r < 4; ++r)
          st[(quad * 4 + r) * 68 + j * 16 + col] =
              __float2bfloat16(acc[i][j][r] * scale + bv4[j]);
      __syncthreads();
      const int row16 = lane >> 2, cseg = lane & 3;
      const long mrow = m0 + wm * 64 + i * 16 + row16;
      bf16_t* cp = (bf16_t*)Cv + (long)z * sC + mrow * ldC + nc0 + cseg * 16;
      const char* sp = stb + row16 * 136 + cseg * 32;
#pragma unroll
      for (int hh = 0; hh < 2; ++hh) {
        uint2 aa = *(const uint2*)(sp + hh * 16);
        uint2 bb = *(const uint2*)(sp + hh * 16 + 8);
        uint4 vv; vv.x = aa.x; vv.y = aa.y; vv.z = bb.x; vv.w = bb.y;
        *(uint4*)(cp + hh * 8) = vv;
      }
    }
  } else {
#pragma unroll
    for (int j = 0; j < 4; ++j) {
      const int ng = n0 + wn * 64 + j * 16 + col;
#pragma unroll
      for (int i = 0; i < 4; ++i) {
        const int mg = m0 + wm * 64 + i * 16 + quad * 4;
#pragma unroll
        for (int r = 0; r < 4; ++r)
          ((float*)Cv)[(long)z * sC + (long)(mg + r) * ldC + ng] =
              acc[i][j][r] * scale + bv4[j];
      }
    }
  }
}

// ---------------- fused q/k/v GEMM ----------------
__global__ __launch_bounds__(256) void gemm_qkv(
    const bf16_t* __restrict__ A, const bf16_t* __restrict__ wT,
    const float* __restrict__ bias_cat, u8* __restrict__ o8,
    u8* __restrict__ vT8)
{
  __shared__ __align__(16) char smem[32768];
  bf16_t* lA = (bf16_t*)smem;
  bf16_t* lB = (bf16_t*)(smem + 16384);
  const int z = blockIdx.z;
  const bf16_t* B = wT + (long)(z + 1) * 262144;
  const float* bz = bias_cat + (long)z * 512;
  const int K = 512;
  const int m0 = blockIdx.y * 128, n0 = blockIdx.x * 128;
  const int tid = threadIdx.x;
  const int w = tid >> 6, lane = tid & 63;
  const int wm = w >> 1, wn = w & 1;

  const int rr = tid >> 2;
  const int cc = (((tid & 3) ^ ((tid >> 3) & 3)) * 8);
  const bf16_t* a0 = A + (long)(m0 + rr) * K + cc;
  const bf16_t* b0 = B + (long)(n0 + rr) * K + cc;
  const long rowskip = (long)64 * K;

  char* lAc = (char*)lA;
  char* lBc = (char*)lB;
  const int ofs0 = w * 1024;
  const int ofs1 = 4096 + w * 1024;

  f32x4 acc[4][4] = {};
  const int quad = lane >> 4;
  const int rsel = lane & 15;
  const int swz = (rsel >> 1) & 3;
  const int kchunkA = (quad ^ swz) * 8;

  for (int kt = 0; kt < 8; ++kt) {
    __syncthreads();
    cp16_to_lds(a0,                 lAc + ofs0);
    cp16_to_lds(a0 + rowskip,       lAc + ofs1);
    cp16_to_lds(a0 + 32,            lAc + 8192 + ofs0);
    cp16_to_lds(a0 + 32 + rowskip,  lAc + 8192 + ofs1);
    cp16_to_lds(b0,                 lBc + ofs0);
    cp16_to_lds(b0 + rowskip,       lBc + ofs1);
    cp16_to_lds(b0 + 32,            lBc + 8192 + ofs0);
    cp16_to_lds(b0 + 32 + rowskip,  lBc + 8192 + ofs1);
    a0 += 64; b0 += 64;
    __syncthreads();

#pragma unroll
    for (int p = 0; p < 2; ++p) {
      const int pb = p * 4096;
      bf16x8 af[4], bfr[4];
#pragma unroll
      for (int i = 0; i < 4; ++i) {
        af[i]  = *(const bf16x8*)&lA[pb + (wm * 64 + i * 16 + rsel) * 32 + kchunkA];
        bfr[i] = *(const bf16x8*)&lB[pb + (wn * 64 + i * 16 + rsel) * 32 + kchunkA];
      }
#pragma unroll
      for (int i = 0; i < 4; ++i)
#pragma unroll
        for (int j = 0; j < 4; ++j)
          acc[i][j] = __builtin_amdgcn_mfma_f32_16x16x32_bf16(af[i], bfr[j], acc[i][j], 0, 0, 0);
    }
  }

  const int col = lane & 15;
  float bv4[4];
#pragma unroll
  for (int j = 0; j < 4; ++j) bv4[j] = bz[n0 + wn * 64 + j * 16 + col];
  const int nc0 = n0 + wn * 64;

  if (z < 2) {
    u8* stb = (u8*)(smem + w * 2176);
    u8* O = o8 + (long)z * 8388608;
#pragma unroll
    for (int i = 0; i < 4; ++i) {
      __syncthreads();
#pragma unroll
      for (int j = 0; j < 4; ++j) {
        uint pk = 0;
        pk = __builtin_amdgcn_cvt_pk_fp8_f32(acc[i][j][0] + bv4[j],
                                             acc[i][j][1] + bv4[j], pk, false);
        pk = __builtin_amdgcn_cvt_pk_fp8_f32(acc[i][j][2] + bv4[j],
                                             acc[i][j][3] + bv4[j], pk, true);
        stb[(quad * 4 + 0) * 72 + j * 16 + col] = (u8)(pk);
        stb[(quad * 4 + 1) * 72 + j * 16 + col] = (u8)(pk >> 8);
        stb[(quad * 4 + 2) * 72 + j * 16 + col] = (u8)(pk >> 16);
        stb[(quad * 4 + 3) * 72 + j * 16 + col] = (u8)(pk >> 24);
      }
      __syncthreads();
      const int trow = lane >> 2, seg = lane & 3;
      const long mrow = m0 + wm * 64 + i * 16 + trow;
      *(uint4*)(O + mrow * 512 + nc0 + seg * 16) =
          *(const uint4*)(stb + trow * 72 + seg * 16);
    }
  } else {
    u8* st8 = (u8*)(smem + w * 2176);
    const int bt = blockIdx.y >> 4;
    const int t0g = (m0 & 2047) + wm * 64;
#pragma unroll
    for (int j = 0; j < 4; ++j) {
      __syncthreads();
#pragma unroll
      for (int i = 0; i < 4; ++i) {
        uint pk = 0;
        pk = __builtin_amdgcn_cvt_pk_fp8_f32(acc[i][j][0] + bv4[j],
                                             acc[i][j][1] + bv4[j], pk, false);
        pk = __builtin_amdgcn_cvt_pk_fp8_f32(acc[i][j][2] + bv4[j],
                                             acc[i][j][3] + bv4[j], pk, true);
        *(uint*)&st8[col * 72 + i * 16 + quad * 4] = pk;
      }
      __syncthreads();
      const int drow = lane >> 2, seg = lane & 3;
      const int d = nc0 + j * 16 + drow;
      u8* dst = vT8 + ((long)(bt * 512 + d)) * 2048 + t0g;
      *(uint4*)(dst + seg * 16) = *(const uint4*)(st8 + drow * 72 + seg * 16);
    }
  }
}

// ---------------- generalized fp8 GEMM ----------------
__global__ __launch_bounds__(256) void gemm_fp8(
    const u8* __restrict__ A, const u8* __restrict__ B,
    bf16_t* __restrict__ C, float scale, int K,
    long sA, long sB, long sC, int ldC)
{
  __shared__ __align__(16) char smem[32768];
  const int z = blockIdx.z;
  A += (long)z * sA;
  B += (long)z * sB;
  const int m0 = blockIdx.y * 128, n0 = blockIdx.x * 128;
  const int tid = threadIdx.x;
  const int w = tid >> 6, lane = tid & 63;
  const int wm = w >> 1, wn = w & 1;

  const int rr = tid >> 2;
  const int ccB = (((tid & 3) ^ ((tid >> 3) & 3)) * 16);
  const u8* a0 = A + (long)(m0 + rr) * K + ccB;
  const u8* b0 = B + (long)(n0 + rr) * K + ccB;
  const long rowskip = (long)64 * K;

  char* lAc = smem;
  char* lBc = smem + 16384;
  const int ofs0 = w * 1024;
  const int ofs1 = 4096 + w * 1024;

  f32x4 acc[4][4] = {};
  const int quad = lane >> 4;
  const int rsel = lane & 15;
  const int swz = (rsel >> 1) & 3;

  const int nkt = K >> 7;             // BK=128
  for (int kt = 0; kt < nkt; ++kt) {
    __syncthreads();
    cp16_to_lds(a0,                  lAc + ofs0);
    cp16_to_lds(a0 + rowskip,        lAc + ofs1);
    cp16_to_lds(a0 + 64,             lAc + 8192 + ofs0);
    cp16_to_lds(a0 + 64 + rowskip,   lAc + 8192 + ofs1);
    cp16_to_lds(b0,                  lBc + ofs0);
    cp16_to_lds(b0 + rowskip,        lBc + ofs1);
    cp16_to_lds(b0 + 64,             lBc + 8192 + ofs0);
    cp16_to_lds(b0 + 64 + rowskip,   lBc + 8192 + ofs1);
    a0 += 128; b0 += 128;
    __syncthreads();

#pragma unroll
    for (int p = 0; p < 2; ++p) {
      const int pb = p * 8192;
#pragma unroll
      for (int ks = 0; ks < 2; ++ks) {
        const int gr = ((ks * 2 + (quad >> 1)) ^ swz) * 16 + (quad & 1) * 8;
        long av[4], bv[4];
#pragma unroll
        for (int i = 0; i < 4; ++i) {
          av[i] = *(const long*)(lAc + pb + (wm * 64 + i * 16 + rsel) * 64 + gr);
          bv[i] = *(const long*)(lBc + pb + (wn * 64 + i * 16 + rsel) * 64 + gr);
        }
#pragma unroll
        for (int i = 0; i < 4; ++i)
#pragma unroll
          for (int j = 0; j < 4; ++j)
            acc[i][j] = __builtin_amdgcn_mfma_f32_16x16x32_fp8_fp8(av[i], bv[j], acc[i][j], 0, 0, 0);
      }
    }
  }

  const int col = lane & 15;
  char* stb = smem + w * 2176;
  const int nc0 = n0 + wn * 64;
#pragma unroll
  for (int i = 0; i < 4; ++i) {
    __syncthreads();
    bf16_t* st = (bf16_t*)stb;
#pragma unroll
    for (int j = 0; j < 4; ++j)
#pragma unroll
      for (int r = 0; r < 4; ++r)
        st[(quad * 4 + r) * 68 + j * 16 + col] =
            __float2bfloat16(acc[i][j][r] * scale);
    __syncthreads();
    const int row16 = lane >> 2, cseg = lane & 3;
    const long mrow = m0 + wm * 64 + i * 16 + row16;
    bf16_t* cp = C + (long)z * sC + mrow * ldC + nc0 + cseg * 16;
    const char* sp = stb + row16 * 136 + cseg * 32;
#pragma unroll
    for (int hh = 0; hh < 2; ++hh) {
      uint2 aa = *(const uint2*)(sp + hh * 16);
      uint2 bb = *(const uint2*)(sp + hh * 16 + 8);
      uint4 vv; vv.x = aa.x; vv.y = aa.y; vv.z = bb.x; vv.w = bb.y;
      *(uint4*)(cp + hh * 8) = vv;
    }
  }
}

// ---------------- small kernels ----------------
__global__ __launch_bounds__(256) void weight_prep(
    const float* __restrict__ w0, const float* __restrict__ w1,
    const float* __restrict__ w2, const float* __restrict__ w3,
    const float* __restrict__ w4,
    const float* __restrict__ bq, const float* __restrict__ bk,
    const float* __restrict__ bv,
    bf16_t* __restrict__ outT, float* __restrict__ bias_cat)
{
  const int z = blockIdx.z;
  const int N = (z == 4) ? 256 : 512;
  if (z == 4 && blockIdx.y >= 4) return;
  const float* in = (z == 0) ? w0 : (z == 1) ? w1 : (z == 2) ? w2 : (z == 3) ? w3 : w4;
  bf16_t* out = outT + (long)z * 262144;
  const int k0 = blockIdx.x * 64, n0 = blockIdx.y * 64;
  __shared__ bf16_t tile[64 * 66];
  const int tid = threadIdx.x;
  const int r = tid >> 2, c4 = tid & 3;
  const float* src = in + (long)(k0 + r) * N + n0 + c4 * 16;
  uint* dst = (uint*)&tile[r * 66 + c4 * 16];
  float4 f0 = ((const float4*)src)[0], f1 = ((const float4*)src)[1];
  float4 f2 = ((const float4*)src)[2], f3 = ((const float4*)src)[3];
  dst[0] = pk2(f0.x, f0.y); dst[1] = pk2(f0.z, f0.w);
  dst[2] = pk2(f1.x, f1.y); dst[3] = pk2(f1.z, f1.w);
  dst[4] = pk2(f2.x, f2.y); dst[5] = pk2(f2.z, f2.w);
  dst[6] = pk2(f3.x, f3.y); dst[7] = pk2(f3.z, f3.w);
  __syncthreads();
  bf16_t* og = out + (long)(n0 + r) * 512 + k0 + c4 * 16;
  uint ov[8];
#pragma unroll
  for (int j = 0; j < 16; j += 2) {
    const ushort lo = *(const ushort*)&tile[(c4 * 16 + j) * 66 + r];
    const ushort hi = *(const ushort*)&tile[(c4 * 16 + j + 1) * 66 + r];
    ov[j >> 1] = ((uint)hi << 16) | lo;
  }
  uint4 o0, o1;
  o0.x = ov[0]; o0.y = ov[1]; o0.z = ov[2]; o0.w = ov[3];
  o1.x = ov[4]; o1.y = ov[5]; o1.z = ov[6]; o1.w = ov[7];
  ((uint4*)og)[0] = o0;
  ((uint4*)og)[1] = o1;
  if (z >= 1 && z <= 3 && blockIdx.x == 0 && blockIdx.y == 0) {
    const float* bs = (z == 1) ? bq : (z == 2) ? bk : bv;
    bias_cat[(z - 1) * 512 + tid] = bs[tid];
    bias_cat[(z - 1) * 512 + 256 + tid] = bs[256 + tid];
  }
}

__global__ __launch_bounds__(256) void cast_bf16_v(
    const float4* __restrict__ in, uint2* __restrict__ o, int n4) {
  const int i = blockIdx.x * 256 + threadIdx.x;
  if (i < n4) {
    const float4 f = in[i];
    uint2 r; r.x = pk2(f.x, f.y); r.y = pk2(f.z, f.w);
    o[i] = r;
  }
}

// coords [8][2048][3] f32 + mask int -> xy [8][2048][2] f32, m8 [8][2048] u8
__global__ __launch_bounds__(256) void pack_xy(
    const float* __restrict__ coords, const int* __restrict__ mask,
    float* __restrict__ xy, u8* __restrict__ m8)
{
  const int i = blockIdx.x * 256 + threadIdx.x;   // 16384 total
  const float x = coords[(long)i * 3];
  const float y = coords[(long)i * 3 + 1];
  float2 v; v.x = x; v.y = y;
  *(float2*)(xy + (long)i * 2) = v;
  m8[i] = mask[i] ? 1 : 0;
}

// in-place LayerNorm(512)+ReLU, one wave per row, 8 bf16/lane, shuffle-only.
__global__ __launch_bounds__(256) void ln_relu_h(
    bf16_t* __restrict__ X, const float* __restrict__ g, const float* __restrict__ b)
{
  const int tid = threadIdx.x;
  const int lane = tid & 63, w = tid >> 6;
  const long row = (long)blockIdx.x * 4 + w;
  bf16_t* xp = X + row * 512 + lane * 8;
  const uint4 pkv = *(const uint4*)xp;
  const uint va[4] = {pkv.x, pkv.y, pkv.z, pkv.w};
  float v[8];
  float s = 0.0f, q = 0.0f;
#pragma unroll
  for (int i = 0; i < 4; ++i) {
    v[2 * i] = bflo(va[i]); v[2 * i + 1] = bfhi(va[i]);
    s += v[2 * i] + v[2 * i + 1];
    q += v[2 * i] * v[2 * i] + v[2 * i + 1] * v[2 * i + 1];
  }
  for (int o = 32; o; o >>= 1) { s += __shfl_down(s, o); q += __shfl_down(q, o); }
  s = __shfl(s, 0); q = __shfl(q, 0);
  const float mu = s * (1.0f / 512.0f);
  const float rs = rsqrtf(q * (1.0f / 512.0f) - mu * mu + 1e-5f);
  const float4 g0 = ((const float4*)(g + lane * 8))[0], g1 = ((const float4*)(g + lane * 8))[1];
  const float4 b0 = ((const float4*)(b + lane * 8))[0], b1 = ((const float4*)(b + lane * 8))[1];
  const float gg[8] = {g0.x, g0.y, g0.z, g0.w, g1.x, g1.y, g1.z, g1.w};
  const float bb[8] = {b0.x, b0.y, b0.z, b0.w, b1.x, b1.y, b1.z, b1.w};
  uint ov[4];
#pragma unroll
  for (int i = 0; i < 4; ++i) {
    const float y0 = fmaxf((v[2 * i] - mu) * rs * gg[2 * i] + bb[2 * i], 0.0f);
    const float y1 = fmaxf((v[2 * i + 1] - mu) * rs * gg[2 * i + 1] + bb[2 * i + 1], 0.0f);
    ov[i] = pk2(y0, y1);
  }
  uint4 st; st.x = ov[0]; st.y = ov[1]; st.z = ov[2]; st.w = ov[3];
  *(uint4*)xp = st;
}

// softmax over 2048 + *exp(-5 dist) * (!mask) -> fp8(val*256).
// One row per block; xy/m8 pre-packed (coalesced float4 / uint2 loads).
__global__ __launch_bounds__(256) void softmax_adj(
    const bf16_t* __restrict__ SC, u8* __restrict__ A8,
    const float* __restrict__ xy, const u8* __restrict__ m8)
{
  const int bs = blockIdx.x;
  const int b = bs >> 11, s = bs & 2047;
  const long base = (long)bs * 2048;
  const int tid = threadIdx.x;
  const int t0 = tid * 8;
  const uint4 pkv = *(const uint4*)(SC + base + t0);
  const uint va[4] = {pkv.x, pkv.y, pkv.z, pkv.w};
  // own targets' xy: 4 coalesced float4
  const float4* xp = (const float4*)(xy + ((long)b * 2048 + t0) * 2);
  const float4 x0 = xp[0], x1 = xp[1], x2 = xp[2], x3 = xp[3];
  const float cx[8] = {x0.x, x0.z, x1.x, x1.z, x2.x, x2.z, x3.x, x3.z};
  const float cy[8] = {x0.y, x0.w, x1.y, x1.w, x2.y, x2.w, x3.y, x3.w};
  const uint2 mraw = *(const uint2*)(m8 + (long)b * 2048 + t0);
  // query xy (uniform)
  const float px = xy[((long)b * 2048 + s) * 2];
  const float py = xy[((long)b * 2048 + s) * 2 + 1];

  float rv[8];
  float mx = -3.0e38f;
#pragma unroll
  for (int i = 0; i < 4; ++i) {
    rv[2 * i] = bflo(va[i]); rv[2 * i + 1] = bfhi(va[i]);
    mx = fmaxf(mx, fmaxf(rv[2 * i], rv[2 * i + 1]));
  }
  for (int o = 32; o; o >>= 1) mx = fmaxf(mx, __shfl_down(mx, o));
  __shared__ float sm[8];
  const int w = tid >> 6, lane = tid & 63;
  if (!lane) sm[w] = mx;
  __syncthreads();
  mx = fmaxf(fmaxf(sm[0], sm[1]), fmaxf(sm[2], sm[3]));
  float sum = 0.0f;
#pragma unroll
  for (int i = 0; i < 8; ++i) { rv[i] = __expf(rv[i] - mx); sum += rv[i]; }
  for (int o = 32; o; o >>= 1) sum += __shfl_down(sum, o);
  if (!lane) sm[4 + w] = sum;
  __syncthreads();
  const float inv = 256.0f / (sm[4] + sm[5] + sm[6] + sm[7]);   // x256 fp8 scale
  float ov[8];
#pragma unroll
  for (int i = 0; i < 8; ++i) {
    const float dx = px - cx[i], dy = py - cy[i];
    const float adj = __expf(-5.0f * sqrtf(dx * dx + dy * dy));
    const uint mv = (i < 4) ? ((mraw.x >> (8 * i)) & 255u)
                            : ((mraw.y >> (8 * (i - 4))) & 255u);
    ov[i] = mv ? 0.0f : rv[i] * inv * adj;
  }
  uint p0 = 0, p1 = 0;
  p0 = __builtin_amdgcn_cvt_pk_fp8_f32(ov[0], ov[1], p0, false);
  p0 = __builtin_amdgcn_cvt_pk_fp8_f32(ov[2], ov[3], p0, true);
  p1 = __builtin_amdgcn_cvt_pk_fp8_f32(ov[4], ov[5], p1, false);
  p1 = __builtin_amdgcn_cvt_pk_fp8_f32(ov[6], ov[7], p1, true);
  uint2 st; st.x = p0; st.y = p1;
  *(uint2*)(A8 + base + t0) = st;
}

// LayerNorm(256)+ReLU on f32 rows, masked accumulate into pooled_acc[b][256]
__global__ __launch_bounds__(256) void ln2_pool(
    const float* __restrict__ X, const float* __restrict__ g, const float* __restrict__ bt,
    const int* __restrict__ mask, float* __restrict__ pacc)
{
  const int tid = threadIdx.x;
  const int row0 = blockIdx.x * 16;
  const int w = tid >> 6, lane = tid & 63;
  __shared__ float sm[8];
  const float gv = g[tid], bv = bt[tid];
  float acc = 0.0f;
  for (int r = 0; r < 16; ++r) {
    const int row = row0 + r;
    const float x = X[(long)row * 256 + tid];
    float s = x, q = x * x;
    for (int o = 32; o; o >>= 1) { s += __shfl_down(s, o); q += __shfl_down(q, o); }
    if (!lane) { sm[w] = s; sm[4 + w] = q; }
    __syncthreads();
    const float S = sm[0] + sm[1] + sm[2] + sm[3];
    const float Q = sm[4] + sm[5] + sm[6] + sm[7];
    const float mu = S * (1.0f / 256.0f);
    const float rs = rsqrtf(Q * (1.0f / 256.0f) - mu * mu + 1e-5f);
    const float y = fmaxf((x - mu) * rs * gv + bv, 0.0f);
    if (!mask[row]) acc += y;
    __syncthreads();
  }
  atomicAdd(&pacc[(row0 >> 11) * 256 + tid], acc);
}

__global__ __launch_bounds__(256) void classifier_k(
    const float* __restrict__ pacc, const int* __restrict__ mask,
    const float* __restrict__ w1, const float* __restrict__ b1,
    const float* __restrict__ w2, const float* __restrict__ b2,
    float* __restrict__ out)
{
  const int tid = threadIdx.x;
  __shared__ float pooled[2048];
  __shared__ float hidden[1024];
  __shared__ float cnt[8];
  if (tid < 8) cnt[tid] = 0.0f;
  __syncthreads();
  {
    const int* mb = mask + tid * 64;
    int c = 0;
#pragma unroll 8
    for (int i = 0; i < 64; ++i) c += mb[i] ? 0 : 1;
    atomicAdd(&cnt[tid >> 5], (float)c);
  }
  __syncthreads();
  for (int i = tid; i < 2048; i += 256) {
    const float p = pacc[i] / fmaxf(cnt[i >> 8], 1e-9f);
    pooled[i] = p;
    out[80 + i] = p;
  }
  __syncthreads();
  for (int o = tid; o < 1024; o += 256) {
    const int bb = o >> 7, j = o & 127;
    float s = b1[j];
    const float* pb = pooled + bb * 256;
    for (int c = 0; c < 256; ++c) s += pb[c] * w1[c * 128 + j];
    hidden[o] = fmaxf(s, 0.0f);
  }
  __syncthreads();
  if (tid < 80) {
    const int bb = tid / 10, j = tid - bb * 10;
    float s = b2[j];
    const float* hb = hidden + bb * 128;
    for (int c = 0; c < 128; ++c) s += hb[c] * w2[c * 10 + j];
    out[tid] = s;
  }
}

extern "C" void kernel_launch(void* const* d_in, const int* in_sizes, int n_in,
                              void* d_out, int out_size, void* d_ws, size_t ws_size,
                              hipStream_t stream)
{
  const float* lf   = (const float*)d_in[0];
  const float* co   = (const float*)d_in[1];
  const int*   mk   = (const int*)d_in[2];
  const float* wenc = (const float*)d_in[3];
  const float* benc = (const float*)d_in[4];
  const float* g1   = (const float*)d_in[5];
  const float* be1  = (const float*)d_in[6];
  const float* wq   = (const float*)d_in[7];
  const float* bq   = (const float*)d_in[8];
  const float* wk   = (const float*)d_in[9];
  const float* bk   = (const float*)d_in[10];
  const float* wv   = (const float*)d_in[11];
  const float* bvp  = (const float*)d_in[12];
  const float* wbn  = (const float*)d_in[13];
  const float* bbn  = (const float*)d_in[14];
  const float* g2   = (const float*)d_in[15];
  const float* be2  = (const float*)d_in[16];
  const float* w1   = (const float*)d_in[17];
  const float* b1   = (const float*)d_in[18];
  const float* w2   = (const float*)d_in[19];
  const float* b2   = (const float*)d_in[20];
  float* out = (float*)d_out;
  char* ws = (char*)d_ws;

  bf16_t* featb = (bf16_t*)(ws + 0);              // 16 MB
  bf16_t* wT    = (bf16_t*)(ws + 16777216);       // 5 x 512KB slots
  bf16_t* wencT = wT;
  bf16_t* wbnT  = wT + 4 * 262144;
  float*  bias_cat = (float*)(ws + 19398656);     // 8 KB
  bf16_t* h     = (bf16_t*)(ws + 19406848);       // 16 MB -> ends 36184064
  u8*     q8    = (u8*)(ws + 36184064);           // 16 MB (q8, k8) -> 52961280
  u8*     vT8   = (u8*)(ws + 52961280);           // 8 MB -> 61349888
  bf16_t* sc    = (bf16_t*)(ws + 61349888);       // 64 MB -> 128458752
  u8*     at8   = (u8*)(ws + 128458752);          // 32 MB -> 162013184
  float*  xy    = (float*)(ws + 162013184);       // 128 KB -> 162144256
  u8*     m8    = (u8*)(ws + 162144256);          // 16 KB -> 162160640
  bf16_t* hg    = (bf16_t*)(ws + 0);              // reuse featb
  float*  bnp   = (float*)(ws + 36184064);        // reuse q8/k8 (16 MB f32)
  float*  pacc  = (float*)(ws + 52961280);        // reuse vT8 head (8 KB)

  if (ws_size < 162160640) return;  // fail visibly rather than fault

  cast_bf16_v<<<8192, 256, 0, stream>>>((const float4*)lf, (uint2*)featb, 2097152);
  weight_prep<<<dim3(8, 8, 5), 256, 0, stream>>>(wenc, wq, wk, wv, wbn, bq, bk, bvp,
                                                 wT, bias_cat);
  pack_xy<<<64, 256, 0, stream>>>(co, mk, xy, m8);

  // h_pre = feat @ w_enc + b_enc
  gemm_bt<<<dim3(4, 128, 1), 256, 0, stream>>>(featb, wencT, h, benc, 0, 1.0f, 512,
                                               0, 0, 0, 512, 0);
  ln_relu_h<<<4096, 256, 0, stream>>>(h, g1, be1);
  // q,k (fp8 natural) + v (fp8 transposed) in one launch
  gemm_qkv<<<dim3(4, 128, 3), 256, 0, stream>>>(h, wT, bias_cat, q8, vT8);
  // scores[b] = q_b k_b^T / sqrt(512)  (fp8 in, bf16 out)
  gemm_fp8<<<dim3(16, 16, 8), 256, 0, stream>>>(q8, q8 + 8388608, sc,
                                                0.044194173824159216f, 512,
                                                1048576, 1048576, 4194304, 2048);
  // softmax + adj + mask -> attn8 (fp8 x256)
  softmax_adj<<<16384, 256, 0, stream>>>(sc, at8, xy, m8);
  // hg[b] = attn_b @ v_b  (fp8 in, bf16 out, scale 1/256)
  gemm_fp8<<<dim3(4, 16, 8), 256, 0, stream>>>(at8, vT8, hg, 0.00390625f, 2048,
                                               4194304, 1048576, 1048576, 512);
  // bn_pre = hg @ w_bn + b_bn  (f32 out)
  gemm_bt<<<dim3(2, 128, 1), 256, 0, stream>>>(hg, wbnT, bnp, bbn, 0, 1.0f, 512,
                                               0, 0, 0, 256, 2);
  hipMemsetAsync(pacc, 0, 8192, stream);
  ln2_pool<<<1024, 256, 0, stream>>>(bnp, g2, be2, mk, pacc);
  classifier_k<<<1, 256, 0, stream>>>(pacc, mk, w1, b1, w2, b2, out);
}